// Round 1
// baseline (183.067 us; speedup 1.0000x reference)
//
#include <hip/hip_runtime.h>

// Segment-mean of subtoken embeddings (sorted per-row segment ids) -> token
// embeddings, single fused kernel.
//
// One block owns TPB=8 consecutive tokens of one batch row. The block first
// computes all 9 segment boundaries cooperatively from the sorted seg row:
//   lo(t0)       = #(seg < t0)            (per-wave __ballot + popcount)
//   lo(t0+j+1)   = lo(t0+j) + #(seg == t0+j)   (8-bin LDS histogram)
// This replaces the previous bounds_kernel + start-table (two dependent
// dispatches, 24576 single-token blocks) with one dispatch of 3072 blocks,
// each streaming a contiguous run of rows. No workspace needed.

#define TPB_TOKENS 8

__global__ void __launch_bounds__(192) seg_mean_fused(
    const float* __restrict__ hs,        // [B, S, D] f32
    const int*   __restrict__ seg,       // [B, S] sorted per row, in [0, T)
    const int*   __restrict__ num_tokens_p,
    float*       __restrict__ out,       // [B, T, D]
    int BS_total,                        // B*S
    int BT,                              // B*T
    int D) {
  const int T = num_tokens_p[0];
  const int B = BT / T;
  const int S = BS_total / B;

  const int g0 = blockIdx.x * TPB_TOKENS;   // first global token index
  if (g0 >= BT) return;
  const int gEnd = min(g0 + TPB_TOKENS, BT);

  const int tid  = threadIdx.x;
  const int lane = tid & 63;
  const int d4   = tid;                 // [0, D/4)
  const int rowstride4 = D >> 2;

  __shared__ int sh_bounds[TPB_TOKENS + 1];
  __shared__ int sh_bins[TPB_TOKENS];
  __shared__ int sh_base;
  __shared__ int sh_hi;                 // slow path only

  const int b0    = g0 / T;
  const int bLast = (gEnd - 1) / T;

  if (b0 == bLast) {
    // ---- fast path: all tokens in this group belong to batch row b0 ----
    const int t0   = g0 - b0 * T;
    const int nTok = gEnd - g0;

    if (tid < TPB_TOKENS) sh_bins[tid] = 0;
    if (tid == 0) sh_base = 0;
    __syncthreads();

    const int* __restrict__ srow = seg + (size_t)b0 * S;
    for (int s = tid; s < S; s += blockDim.x) {
      const int v = srow[s];
      unsigned long long m = __ballot(v < t0);
      if (lane == 0) atomicAdd(&sh_base, __popcll(m));
      const int rel = v - t0;
      if (rel >= 0 && rel < nTok) atomicAdd(&sh_bins[rel], 1);  // rare (~11/block)
    }
    __syncthreads();

    if (tid == 0) {
      int acc = sh_base;
      sh_bounds[0] = acc;
      #pragma unroll
      for (int j = 0; j < TPB_TOKENS; ++j) {
        acc += sh_bins[j];
        sh_bounds[j + 1] = acc;
      }
    }
    __syncthreads();

    const float4* __restrict__ base =
        (const float4*)(hs + (size_t)b0 * S * D) + d4;

    for (int j = 0; j < nTok; ++j) {
      const int lo  = sh_bounds[j];
      const int cnt = sh_bounds[j + 1] - lo;

      float4 acc = make_float4(0.f, 0.f, 0.f, 0.f);
      const float4* __restrict__ p = base + (size_t)lo * rowstride4;
      for (int s = 0; s < cnt; ++s) {
        float4 v = p[(size_t)s * rowstride4];
        acc.x += v.x; acc.y += v.y; acc.z += v.z; acc.w += v.w;
      }
      const float inv = (cnt > 0) ? (1.0f / (float)cnt) : 0.0f;
      float4 o = make_float4(acc.x * inv, acc.y * inv, acc.z * inv, acc.w * inv);
      ((float4*)(out + (size_t)(g0 + j) * D))[d4] = o;
    }
  } else {
    // ---- slow path: group straddles a batch-row boundary (only when
    // T % TPB_TOKENS != 0). Per-token cooperative count. ----
    for (int g = g0; g < gEnd; ++g) {
      const int b = g / T;
      const int t = g - b * T;

      if (tid == 0) { sh_base = 0; sh_hi = 0; }
      __syncthreads();

      const int* __restrict__ srow = seg + (size_t)b * S;
      for (int s = tid; s < S; s += blockDim.x) {
        const int v = srow[s];
        unsigned long long mlo = __ballot(v < t);
        unsigned long long mhi = __ballot(v < t + 1);
        if (lane == 0) {
          atomicAdd(&sh_base, __popcll(mlo));
          atomicAdd(&sh_hi,   __popcll(mhi));
        }
      }
      __syncthreads();

      const int lo  = sh_base;
      const int cnt = sh_hi - lo;

      float4 acc = make_float4(0.f, 0.f, 0.f, 0.f);
      const float4* __restrict__ p =
          (const float4*)(hs + ((size_t)b * S + lo) * D) + d4;
      for (int s = 0; s < cnt; ++s) {
        float4 v = p[(size_t)s * rowstride4];
        acc.x += v.x; acc.y += v.y; acc.z += v.z; acc.w += v.w;
      }
      const float inv = (cnt > 0) ? (1.0f / (float)cnt) : 0.0f;
      float4 o = make_float4(acc.x * inv, acc.y * inv, acc.z * inv, acc.w * inv);
      ((float4*)(out + (size_t)g * D))[d4] = o;

      __syncthreads();   // protect sh_base/sh_hi reuse next token
    }
  }
}

extern "C" void kernel_launch(void* const* d_in, const int* in_sizes, int n_in,
                              void* d_out, int out_size, void* d_ws, size_t ws_size,
                              hipStream_t stream) {
  const float* hs = (const float*)d_in[0];
  const int* seg = (const int*)d_in[1];
  const int* num_tokens_p = (const int*)d_in[2];
  float* out = (float*)d_out;

  const int BS_total = in_sizes[1];            // B*S
  const int D = in_sizes[0] / in_sizes[1];     // 768
  const int BT = out_size / D;                 // B*T

  const int grid = (BT + TPB_TOKENS - 1) / TPB_TOKENS;
  hipLaunchKernelGGL(seg_mean_fused, dim3(grid), dim3(D / 4), 0, stream,
                     hs, seg, num_tokens_p, out, BS_total, BT, D);
}

// Round 3
// 177.954 us; speedup vs baseline: 1.0287x; 1.0287x over previous
//
#include <hip/hip_runtime.h>

// Segment-mean of subtoken embeddings (sorted per-row segment ids) -> token means.
//
// Phase 1 (bounds_pairs_kernel): each subtoken thread s owns tokens
//   t in (seg[s-1], seg[s]] and writes pairs[b*T+t] = {global_lo, global_hi}
//   as GLOBAL row indices (b*S + s). One write per field, no races.
//   Removes all per-block search/scan latency from phase 2.
// Phase 2 (seg_mean_d768): persistent grid-stride kernel, ONE WAVE PER TOKEN.
//   2048 blocks x 256 threads = 8 blocks/CU x 4 waves = 32 waves/CU (full
//   occupancy, no straggler tail — round 1's 52% occupancy was a 341-block
//   tail at ~12%). Each lane owns 3 float4 columns of D=768 -> 3 independent
//   loads in flight per row. Next-token bounds prefetched so the dependent
//   int2 load hides under the current token's streaming.

#define PHASE2_WAVES 4   // waves (= tokens in flight) per block

__global__ void bounds_pairs_kernel(const int* __restrict__ seg,
                                    const int* __restrict__ num_tokens_p,
                                    int2* __restrict__ pairs,   // [B*T] global-row bounds
                                    int BS_total,               // B*S
                                    int BT) {                   // B*T
  const int T = num_tokens_p[0];
  const int B = BT / T;
  const int S = BS_total / B;
  const int idx = blockIdx.x * blockDim.x + threadIdx.x;
  if (idx >= BS_total) return;
  const int b = idx / S;
  const int s = idx - b * S;
  const int cur = seg[idx];
  const int prev = (s == 0) ? -1 : seg[idx - 1];
  int2* __restrict__ prow = pairs + (size_t)b * T;

  // tokens whose lower bound is row s: t in (prev, cur]
  for (int t = prev + 1; t <= cur; ++t) {
    prow[t].x = idx;                 // lo(t) = global row idx; t <= cur < T
    if (t > 0) prow[t - 1].y = idx;  // hi(t-1) = lo(t)
  }
  // tail: tokens beyond the last segment id get lo = hi = end of this row
  if (s == S - 1) {
    const int end = b * S + S;
    for (int t = cur + 1; t <= T; ++t) {
      if (t < T) prow[t].x = end;
      prow[t - 1].y = end;
    }
  }
}

// Specialized for D == 768 (dv4 = 192 = 3 float4 per lane).
__global__ void __launch_bounds__(64 * PHASE2_WAVES) seg_mean_d768(
    const float* __restrict__ hs,      // [B, S, 768]
    const int2*  __restrict__ pairs,   // [B*T]
    float*       __restrict__ out,     // [B, T, 768]
    int BT) {
  const int wave = threadIdx.x >> 6;
  const int lane = threadIdx.x & 63;
  const int gstride = gridDim.x * PHASE2_WAVES;

  int g = blockIdx.x * PHASE2_WAVES + wave;
  if (g >= BT) return;
  int2 lh = pairs[g];

  while (true) {
    const int gn = g + gstride;
    int2 lh_next;
    if (gn < BT) lh_next = pairs[gn];   // prefetch next token's bounds

    const int cnt = lh.y - lh.x;
    const float4* __restrict__ p =
        (const float4*)hs + (size_t)lh.x * 192 + lane;

    float4 a0 = make_float4(0.f, 0.f, 0.f, 0.f);
    float4 a1 = a0, a2 = a0;
    for (int r = 0; r < cnt; ++r) {
      float4 v0 = p[0];
      float4 v1 = p[64];
      float4 v2 = p[128];
      a0.x += v0.x; a0.y += v0.y; a0.z += v0.z; a0.w += v0.w;
      a1.x += v1.x; a1.y += v1.y; a1.z += v1.z; a1.w += v1.w;
      a2.x += v2.x; a2.y += v2.y; a2.z += v2.z; a2.w += v2.w;
      p += 192;
    }

    const float inv = (cnt > 0) ? (1.0f / (float)cnt) : 0.0f;
    float4* __restrict__ q = (float4*)out + (size_t)g * 192 + lane;
    q[0]   = make_float4(a0.x * inv, a0.y * inv, a0.z * inv, a0.w * inv);
    q[64]  = make_float4(a1.x * inv, a1.y * inv, a1.z * inv, a1.w * inv);
    q[128] = make_float4(a2.x * inv, a2.y * inv, a2.z * inv, a2.w * inv);

    if (gn >= BT) break;
    g = gn;
    lh = lh_next;
  }
}

// Generic-D fallback (D % 4 == 0): one wave per token, column-strided.
__global__ void __launch_bounds__(64 * PHASE2_WAVES) seg_mean_generic(
    const float* __restrict__ hs,
    const int2*  __restrict__ pairs,
    float*       __restrict__ out,
    int BT,
    int dv4) {
  const int wave = threadIdx.x >> 6;
  const int lane = threadIdx.x & 63;
  const int gstride = gridDim.x * PHASE2_WAVES;

  for (int g = blockIdx.x * PHASE2_WAVES + wave; g < BT; g += gstride) {
    const int2 lh = pairs[g];
    const int cnt = lh.y - lh.x;
    const float inv = (cnt > 0) ? (1.0f / (float)cnt) : 0.0f;

    for (int c = lane; c < dv4; c += 64) {
      const float4* __restrict__ p = (const float4*)hs + (size_t)lh.x * dv4 + c;
      float4 acc = make_float4(0.f, 0.f, 0.f, 0.f);
      for (int r = 0; r < cnt; ++r) {
        float4 v = *p;
        acc.x += v.x; acc.y += v.y; acc.z += v.z; acc.w += v.w;
        p += dv4;
      }
      ((float4*)(out + (size_t)g * (dv4 * 4)))[c] =
          make_float4(acc.x * inv, acc.y * inv, acc.z * inv, acc.w * inv);
    }
  }
}

// Workspace-too-small fallback (round-1 style, correctness only).
__global__ void __launch_bounds__(192) seg_mean_search_kernel(
    const float* __restrict__ hs,
    const int* __restrict__ seg,
    const int* __restrict__ num_tokens_p,
    float* __restrict__ out,
    int BS_total,
    int D) {
  const int T = num_tokens_p[0];
  const int BT = gridDim.x;
  const int S = (int)(((long long)BS_total * T) / BT);
  const int b = blockIdx.x / T;
  const int t = blockIdx.x - b * T;
  const int* __restrict__ row = seg + (size_t)b * S;

  int lo = 0, n = S;
  while (n > 0) {
    int half = n >> 1;
    int mid = lo + half;
    if (row[mid] < t) { lo = mid + 1; n -= half + 1; } else { n = half; }
  }
  int hi = lo; n = S - lo;
  while (n > 0) {
    int half = n >> 1;
    int mid = hi + half;
    if (row[mid] < t + 1) { hi = mid + 1; n -= half + 1; } else { n = half; }
  }
  const int cnt = hi - lo;

  const int d4 = threadIdx.x;
  const int rowstride4 = D >> 2;
  const float4* __restrict__ p =
      (const float4*)(hs + ((size_t)b * S + lo) * D) + d4;

  float4 acc = make_float4(0.f, 0.f, 0.f, 0.f);
  for (int s = 0; s < cnt; ++s) {
    float4 v = p[(size_t)s * rowstride4];
    acc.x += v.x; acc.y += v.y; acc.z += v.z; acc.w += v.w;
  }
  const float inv = (cnt > 0) ? (1.0f / (float)cnt) : 0.0f;
  float4 o = make_float4(acc.x * inv, acc.y * inv, acc.z * inv, acc.w * inv);
  ((float4*)(out + (size_t)blockIdx.x * D))[d4] = o;
}

extern "C" void kernel_launch(void* const* d_in, const int* in_sizes, int n_in,
                              void* d_out, int out_size, void* d_ws, size_t ws_size,
                              hipStream_t stream) {
  const float* hs = (const float*)d_in[0];
  const int* seg = (const int*)d_in[1];
  const int* num_tokens_p = (const int*)d_in[2];
  float* out = (float*)d_out;

  const int BS_total = in_sizes[1];            // B*S
  const int D = in_sizes[0] / in_sizes[1];     // 768
  const int BT = out_size / D;                 // B*T

  const size_t ws_needed = (size_t)8 * (size_t)BT;   // int2 per token

  if (ws_size >= ws_needed) {
    int2* pairs = (int2*)d_ws;

    const int threads1 = 256;
    const int grid1 = (BS_total + threads1 - 1) / threads1;
    hipLaunchKernelGGL(bounds_pairs_kernel, dim3(grid1), dim3(threads1), 0, stream,
                       seg, num_tokens_p, pairs, BS_total, BT);

    // Full-occupancy persistent grid: 8 blocks/CU x 4 waves = 32 waves/CU.
    const int maxBlocks = 2048;
    const int needBlocks = (BT + PHASE2_WAVES - 1) / PHASE2_WAVES;
    const int grid2 = (needBlocks < maxBlocks) ? needBlocks : maxBlocks;

    if (D == 768) {
      hipLaunchKernelGGL(seg_mean_d768, dim3(grid2), dim3(64 * PHASE2_WAVES), 0,
                         stream, hs, pairs, out, BT);
    } else {
      hipLaunchKernelGGL(seg_mean_generic, dim3(grid2), dim3(64 * PHASE2_WAVES), 0,
                         stream, hs, pairs, out, BT, D / 4);
    }
  } else {
    hipLaunchKernelGGL(seg_mean_search_kernel, dim3(BT), dim3(D / 4), 0, stream,
                       hs, seg, num_tokens_p, out, BS_total, D);
  }
}

// Round 4
// 177.733 us; speedup vs baseline: 1.0300x; 1.0012x over previous
//
#include <hip/hip_runtime.h>

// Segment-mean of subtoken embeddings (sorted per-row segment ids) -> token means.
//
// Phase 1 (bounds_pairs_kernel): pairs[b*T+t] = {global_lo, global_hi} row
//   bounds per token (each field written exactly once; sorted ids => ownership
//   partition). ~2 us.
// Phase 2 (seg_mean_span_d768): the streaming phase. Diagnosis from rounds
//   0/1/3: every prior structure let each wave have only ~4 loads in flight
//   before a full vmcnt(0) drain (cnt avg = S/T = 1.33 rows/token) -> 2.1 TB/s
//   regardless of occupancy. Here each wave owns K=4 CONSECUTIVE tokens = one
//   contiguous row run [start(g0), start(g0+4)), streamed through a 4-deep
//   hand-unrolled software pipeline (static buffers A..D, 12 float4 loads in
//   flight per lane). Token flush logic is wave-uniform (boundary compares on
//   a shifting register queue), handles empty tokens (writes zeros) and
//   trailing empties. No LDS, no atomics, no cross-wave interaction.

#define SPAN_K 4           // tokens per wave
#define WPB    4           // waves per block (256 threads)

__global__ void bounds_pairs_kernel(const int* __restrict__ seg,
                                    const int* __restrict__ num_tokens_p,
                                    int2* __restrict__ pairs,   // [B*T] global-row bounds
                                    int BS_total,               // B*S
                                    int BT) {                   // B*T
  const int T = num_tokens_p[0];
  const int B = BT / T;
  const int S = BS_total / B;
  const int idx = blockIdx.x * blockDim.x + threadIdx.x;
  if (idx >= BS_total) return;
  const int b = idx / S;
  const int s = idx - b * S;
  const int cur = seg[idx];
  const int prev = (s == 0) ? -1 : seg[idx - 1];
  int2* __restrict__ prow = pairs + (size_t)b * T;

  for (int t = prev + 1; t <= cur; ++t) {
    prow[t].x = idx;                 // lo(t): global row index
    if (t > 0) prow[t - 1].y = idx;  // hi(t-1) = lo(t)
  }
  if (s == S - 1) {
    const int end = b * S + S;
    for (int t = cur + 1; t <= T; ++t) {
      if (t < T) prow[t].x = end;
      prow[t - 1].y = end;
    }
  }
}

// D == 768 specialization: lane owns float4 columns {lane, lane+64, lane+128}.
__global__ void __launch_bounds__(64 * WPB, 4) seg_mean_span_d768(
    const float* __restrict__ hs,      // [B, S, 768]
    const int2*  __restrict__ pairs,   // [B*T]
    float*       __restrict__ out,     // [B, T, 768]
    int BT) {
  const int wave = threadIdx.x >> 6;
  const int lane = threadIdx.x & 63;
  const int g0 = (blockIdx.x * WPB + wave) * SPAN_K;
  if (g0 >= BT) return;
  const int nTok = (BT - g0 < SPAN_K) ? (BT - g0) : SPAN_K;

  // Wave-uniform boundaries s0..s4 (global row indices), all loads independent.
  const int2 pL = pairs[g0 + nTok - 1];
  const int sEnd = pL.y;
  const int s0 = pairs[g0].x;
  const int s1 = (nTok > 1) ? pairs[g0 + 1].x : sEnd;
  const int s2 = (nTok > 2) ? pairs[g0 + 2].x : sEnd;
  const int s3 = (nTok > 3) ? pairs[g0 + 3].x : sEnd;
  const int s4 = sEnd;

  const float4* __restrict__ hsv = (const float4*)hs;

#define ISSUE(X0, X1, X2, ROW)                                   \
  do {                                                           \
    const float4* _p = hsv + (size_t)(ROW) * 192 + lane;         \
    X0 = _p[0]; X1 = _p[64]; X2 = _p[128];                       \
  } while (0)

  float4 A0, A1, A2, B0, B1, B2, C0, C1, C2, D0, D1, D2;
  int rowI = s0;                       // issue cursor
  if (rowI < s4) { ISSUE(A0, A1, A2, rowI); ++rowI; }
  if (rowI < s4) { ISSUE(B0, B1, B2, rowI); ++rowI; }
  if (rowI < s4) { ISSUE(C0, C1, C2, rowI); ++rowI; }
  if (rowI < s4) { ISSUE(D0, D1, D2, rowI); ++rowI; }

  float4 acc0 = make_float4(0.f, 0.f, 0.f, 0.f);
  float4 acc1 = acc0, acc2 = acc0;
  int rowC = s0;                       // consume cursor
  int tok = 0;                         // tokens flushed
  int curLo = s0;
  int nb1 = s1, nb2 = s2, nb3 = s3;    // boundary shift queue (next = nb1)

  // Flush every token whose end boundary == rowC (handles empties: cnt==0 ->
  // inv=0 -> stores zeros). All conditions wave-uniform.
#define FLUSH()                                                               \
  while (tok < nTok && rowC == nb1) {                                         \
    const int _cnt = rowC - curLo;                                            \
    const float _inv = (_cnt > 0) ? (1.0f / (float)_cnt) : 0.0f;              \
    float4* _q = (float4*)out + (size_t)(g0 + tok) * 192 + lane;              \
    _q[0]   = make_float4(acc0.x * _inv, acc0.y * _inv, acc0.z * _inv, acc0.w * _inv); \
    _q[64]  = make_float4(acc1.x * _inv, acc1.y * _inv, acc1.z * _inv, acc1.w * _inv); \
    _q[128] = make_float4(acc2.x * _inv, acc2.y * _inv, acc2.z * _inv, acc2.w * _inv); \
    acc0 = make_float4(0.f, 0.f, 0.f, 0.f); acc1 = acc0; acc2 = acc0;         \
    curLo = rowC; ++tok;                                                      \
    nb1 = nb2; nb2 = nb3; nb3 = s4;                                           \
  }

#define CONSUME(X0, X1, X2)                                                   \
  do {                                                                        \
    acc0.x += X0.x; acc0.y += X0.y; acc0.z += X0.z; acc0.w += X0.w;           \
    acc1.x += X1.x; acc1.y += X1.y; acc1.z += X1.z; acc1.w += X1.w;           \
    acc2.x += X2.x; acc2.y += X2.y; acc2.z += X2.z; acc2.w += X2.w;           \
    ++rowC;                                                                   \
  } while (0)

  FLUSH();   // leading / all-empty spans
  while (rowC < s4) {
    CONSUME(A0, A1, A2);
    if (rowI < s4) { ISSUE(A0, A1, A2, rowI); ++rowI; }
    FLUSH();
    if (rowC >= s4) break;

    CONSUME(B0, B1, B2);
    if (rowI < s4) { ISSUE(B0, B1, B2, rowI); ++rowI; }
    FLUSH();
    if (rowC >= s4) break;

    CONSUME(C0, C1, C2);
    if (rowI < s4) { ISSUE(C0, C1, C2, rowI); ++rowI; }
    FLUSH();
    if (rowC >= s4) break;

    CONSUME(D0, D1, D2);
    if (rowI < s4) { ISSUE(D0, D1, D2, rowI); ++rowI; }
    FLUSH();
  }

#undef CONSUME
#undef FLUSH
#undef ISSUE
}

// Generic-D fallback (D % 4 == 0): one wave per token, column-strided.
__global__ void __launch_bounds__(256) seg_mean_generic(
    const float* __restrict__ hs,
    const int2*  __restrict__ pairs,
    float*       __restrict__ out,
    int BT,
    int dv4) {
  const int wave = threadIdx.x >> 6;
  const int lane = threadIdx.x & 63;
  const int gstride = gridDim.x * 4;

  for (int g = blockIdx.x * 4 + wave; g < BT; g += gstride) {
    const int2 lh = pairs[g];
    const int cnt = lh.y - lh.x;
    const float inv = (cnt > 0) ? (1.0f / (float)cnt) : 0.0f;

    for (int c = lane; c < dv4; c += 64) {
      const float4* __restrict__ p = (const float4*)hs + (size_t)lh.x * dv4 + c;
      float4 acc = make_float4(0.f, 0.f, 0.f, 0.f);
      for (int r = 0; r < cnt; ++r) {
        float4 v = *p;
        acc.x += v.x; acc.y += v.y; acc.z += v.z; acc.w += v.w;
        p += dv4;
      }
      ((float4*)(out + (size_t)g * (dv4 * 4)))[c] =
          make_float4(acc.x * inv, acc.y * inv, acc.z * inv, acc.w * inv);
    }
  }
}

// Workspace-too-small fallback (correctness only).
__global__ void __launch_bounds__(192) seg_mean_search_kernel(
    const float* __restrict__ hs,
    const int* __restrict__ seg,
    const int* __restrict__ num_tokens_p,
    float* __restrict__ out,
    int BS_total,
    int D) {
  const int T = num_tokens_p[0];
  const int BT = gridDim.x;
  const int S = (int)(((long long)BS_total * T) / BT);
  const int b = blockIdx.x / T;
  const int t = blockIdx.x - b * T;
  const int* __restrict__ row = seg + (size_t)b * S;

  int lo = 0, n = S;
  while (n > 0) {
    int half = n >> 1;
    int mid = lo + half;
    if (row[mid] < t) { lo = mid + 1; n -= half + 1; } else { n = half; }
  }
  int hi = lo; n = S - lo;
  while (n > 0) {
    int half = n >> 1;
    int mid = hi + half;
    if (row[mid] < t + 1) { hi = mid + 1; n -= half + 1; } else { n = half; }
  }
  const int cnt = hi - lo;

  const int d4 = threadIdx.x;
  const int rowstride4 = D >> 2;
  const float4* __restrict__ p =
      (const float4*)(hs + ((size_t)b * S + lo) * D) + d4;

  float4 acc = make_float4(0.f, 0.f, 0.f, 0.f);
  for (int s = 0; s < cnt; ++s) {
    float4 v = p[(size_t)s * rowstride4];
    acc.x += v.x; acc.y += v.y; acc.z += v.z; acc.w += v.w;
  }
  const float inv = (cnt > 0) ? (1.0f / (float)cnt) : 0.0f;
  float4 o = make_float4(acc.x * inv, acc.y * inv, acc.z * inv, acc.w * inv);
  ((float4*)(out + (size_t)blockIdx.x * D))[d4] = o;
}

extern "C" void kernel_launch(void* const* d_in, const int* in_sizes, int n_in,
                              void* d_out, int out_size, void* d_ws, size_t ws_size,
                              hipStream_t stream) {
  const float* hs = (const float*)d_in[0];
  const int* seg = (const int*)d_in[1];
  const int* num_tokens_p = (const int*)d_in[2];
  float* out = (float*)d_out;

  const int BS_total = in_sizes[1];            // B*S
  const int D = in_sizes[0] / in_sizes[1];     // 768
  const int BT = out_size / D;                 // B*T

  const size_t ws_needed = (size_t)8 * (size_t)BT;   // int2 per token

  if (ws_size >= ws_needed) {
    int2* pairs = (int2*)d_ws;

    const int threads1 = 256;
    const int grid1 = (BS_total + threads1 - 1) / threads1;
    hipLaunchKernelGGL(bounds_pairs_kernel, dim3(grid1), dim3(threads1), 0, stream,
                       seg, num_tokens_p, pairs, BS_total, BT);

    if (D == 768) {
      const int tokensPerBlock = SPAN_K * WPB;   // 16
      const int grid2 = (BT + tokensPerBlock - 1) / tokensPerBlock;
      hipLaunchKernelGGL(seg_mean_span_d768, dim3(grid2), dim3(64 * WPB), 0,
                         stream, hs, pairs, out, BT);
    } else {
      const int needBlocks = (BT + 3) / 4;
      const int grid2 = (needBlocks < 2048) ? needBlocks : 2048;
      hipLaunchKernelGGL(seg_mean_generic, dim3(grid2), dim3(256), 0,
                         stream, hs, pairs, out, BT, D / 4);
    }
  } else {
    hipLaunchKernelGGL(seg_mean_search_kernel, dim3(BT), dim3(D / 4), 0, stream,
                       hs, seg, num_tokens_p, out, BS_total, D);
  }
}

// Round 5
// 172.684 us; speedup vs baseline: 1.0601x; 1.0292x over previous
//
#include <hip/hip_runtime.h>

// Segment-mean of subtoken embeddings (sorted per-row segment ids) -> token means.
//
// Round-5 structure: return to the empirically-fastest phase-2 (round 0's
// one-block-per-token tiny-block kernel, ~52us) and strip its overheads:
//   - single int2 bounds load (was 2 int loads)
//   - block-uniform fast paths: cnt==0 (no loads, store zeros), cnt==1 (pure
//     copy, no FADD chain), cnt==2 (two loads, one add) -- covers ~84% of
//     tokens at S/T = 1.33 subtokens/token.
//   - NONTEMPORAL stores for out: the 75 MB write stream no longer allocates
//     in L2/L3, so it stops evicting hs (100 MB, re-read every iteration)
//     mid-kernel. Theory: the ~2.1 TB/s wall shared by rounds 0/1/3/4 is
//     cache churn from the write stream, not latency (in-flight math says
//     latency was always covered).
//
// Phase 1 (bounds_pairs_kernel): pairs[b*T+t] = {global_lo, global_hi} row
// bounds per token; each field written exactly once (sorted ids => ownership).

typedef float f32x4_v __attribute__((ext_vector_type(4)));

__global__ void bounds_pairs_kernel(const int* __restrict__ seg,
                                    const int* __restrict__ num_tokens_p,
                                    int2* __restrict__ pairs,   // [B*T] global-row bounds
                                    int BS_total,               // B*S
                                    int BT) {                   // B*T
  const int T = num_tokens_p[0];
  const int B = BT / T;
  const int S = BS_total / B;
  const int idx = blockIdx.x * blockDim.x + threadIdx.x;
  if (idx >= BS_total) return;
  const int b = idx / S;
  const int s = idx - b * S;
  const int cur = seg[idx];
  const int prev = (s == 0) ? -1 : seg[idx - 1];
  int2* __restrict__ prow = pairs + (size_t)b * T;

  for (int t = prev + 1; t <= cur; ++t) {
    prow[t].x = idx;                 // lo(t): global row index
    if (t > 0) prow[t - 1].y = idx;  // hi(t-1) = lo(t)
  }
  if (s == S - 1) {
    const int end = b * S + S;
    for (int t = cur + 1; t <= T; ++t) {
      if (t < T) prow[t].x = end;
      prow[t - 1].y = end;
    }
  }
}

// One block per token, 192 threads (3 waves), lane owns one float4 column.
__global__ void __launch_bounds__(192) seg_mean_tok_d768(
    const float* __restrict__ hs,      // [B, S, 768]
    const int2*  __restrict__ pairs,   // [B*T]
    float*       __restrict__ out) {   // [B, T, 768]
  const int g = blockIdx.x;
  const int2 lh = pairs[g];            // one 8B broadcast load
  const int cnt = lh.y - lh.x;
  const int d4 = threadIdx.x;          // [0, 192)

  const float4* __restrict__ p =
      (const float4*)hs + (size_t)lh.x * 192 + d4;
  f32x4_v* __restrict__ q = (f32x4_v*)out + (size_t)g * 192 + d4;

  float4 o;
  if (cnt == 1) {                      // ~35% of tokens: pure copy
    o = p[0];
  } else if (cnt == 0) {               // ~26%: zeros, no loads at all
    o = make_float4(0.f, 0.f, 0.f, 0.f);
  } else if (cnt == 2) {               // ~23%: two loads, one add
    float4 a = p[0];
    float4 b = p[192];
    o = make_float4((a.x + b.x) * 0.5f, (a.y + b.y) * 0.5f,
                    (a.z + b.z) * 0.5f, (a.w + b.w) * 0.5f);
  } else {                             // ~16%: general loop, 2-wide unroll
    float4 acc = make_float4(0.f, 0.f, 0.f, 0.f);
    int r = 0;
    for (; r + 1 < cnt; r += 2) {
      float4 a = p[(size_t)r * 192];
      float4 b = p[(size_t)(r + 1) * 192];
      acc.x += a.x + b.x; acc.y += a.y + b.y;
      acc.z += a.z + b.z; acc.w += a.w + b.w;
    }
    if (r < cnt) {
      float4 a = p[(size_t)r * 192];
      acc.x += a.x; acc.y += a.y; acc.z += a.z; acc.w += a.w;
    }
    const float inv = 1.0f / (float)cnt;
    o = make_float4(acc.x * inv, acc.y * inv, acc.z * inv, acc.w * inv);
  }

  // Nontemporal: out is written once and never re-read by this kernel;
  // keep it from evicting hs in L2/L3.
  f32x4_v ov;
  ov.x = o.x; ov.y = o.y; ov.z = o.z; ov.w = o.w;
  __builtin_nontemporal_store(ov, q);
}

// Generic-D fallback (D % 4 == 0): one wave per token, column-strided.
__global__ void __launch_bounds__(256) seg_mean_generic(
    const float* __restrict__ hs,
    const int2*  __restrict__ pairs,
    float*       __restrict__ out,
    int BT,
    int dv4) {
  const int wave = threadIdx.x >> 6;
  const int lane = threadIdx.x & 63;
  const int gstride = gridDim.x * 4;

  for (int g = blockIdx.x * 4 + wave; g < BT; g += gstride) {
    const int2 lh = pairs[g];
    const int cnt = lh.y - lh.x;
    const float inv = (cnt > 0) ? (1.0f / (float)cnt) : 0.0f;

    for (int c = lane; c < dv4; c += 64) {
      const float4* __restrict__ p = (const float4*)hs + (size_t)lh.x * dv4 + c;
      float4 acc = make_float4(0.f, 0.f, 0.f, 0.f);
      for (int r = 0; r < cnt; ++r) {
        float4 v = *p;
        acc.x += v.x; acc.y += v.y; acc.z += v.z; acc.w += v.w;
        p += dv4;
      }
      ((float4*)(out + (size_t)g * (dv4 * 4)))[c] =
          make_float4(acc.x * inv, acc.y * inv, acc.z * inv, acc.w * inv);
    }
  }
}

// Workspace-too-small fallback (correctness only).
__global__ void __launch_bounds__(192) seg_mean_search_kernel(
    const float* __restrict__ hs,
    const int* __restrict__ seg,
    const int* __restrict__ num_tokens_p,
    float* __restrict__ out,
    int BS_total,
    int D) {
  const int T = num_tokens_p[0];
  const int BT = gridDim.x;
  const int S = (int)(((long long)BS_total * T) / BT);
  const int b = blockIdx.x / T;
  const int t = blockIdx.x - b * T;
  const int* __restrict__ row = seg + (size_t)b * S;

  int lo = 0, n = S;
  while (n > 0) {
    int half = n >> 1;
    int mid = lo + half;
    if (row[mid] < t) { lo = mid + 1; n -= half + 1; } else { n = half; }
  }
  int hi = lo; n = S - lo;
  while (n > 0) {
    int half = n >> 1;
    int mid = hi + half;
    if (row[mid] < t + 1) { hi = mid + 1; n -= half + 1; } else { n = half; }
  }
  const int cnt = hi - lo;

  const int d4 = threadIdx.x;
  const int rowstride4 = D >> 2;
  const float4* __restrict__ p =
      (const float4*)(hs + ((size_t)b * S + lo) * D) + d4;

  float4 acc = make_float4(0.f, 0.f, 0.f, 0.f);
  for (int s = 0; s < cnt; ++s) {
    float4 v = p[(size_t)s * rowstride4];
    acc.x += v.x; acc.y += v.y; acc.z += v.z; acc.w += v.w;
  }
  const float inv = (cnt > 0) ? (1.0f / (float)cnt) : 0.0f;
  float4 o = make_float4(acc.x * inv, acc.y * inv, acc.z * inv, acc.w * inv);
  ((float4*)(out + (size_t)blockIdx.x * D))[d4] = o;
}

extern "C" void kernel_launch(void* const* d_in, const int* in_sizes, int n_in,
                              void* d_out, int out_size, void* d_ws, size_t ws_size,
                              hipStream_t stream) {
  const float* hs = (const float*)d_in[0];
  const int* seg = (const int*)d_in[1];
  const int* num_tokens_p = (const int*)d_in[2];
  float* out = (float*)d_out;

  const int BS_total = in_sizes[1];            // B*S
  const int D = in_sizes[0] / in_sizes[1];     // 768
  const int BT = out_size / D;                 // B*T

  const size_t ws_needed = (size_t)8 * (size_t)BT;   // int2 per token

  if (ws_size >= ws_needed) {
    int2* pairs = (int2*)d_ws;

    const int threads1 = 256;
    const int grid1 = (BS_total + threads1 - 1) / threads1;
    hipLaunchKernelGGL(bounds_pairs_kernel, dim3(grid1), dim3(threads1), 0, stream,
                       seg, num_tokens_p, pairs, BS_total, BT);

    if (D == 768) {
      hipLaunchKernelGGL(seg_mean_tok_d768, dim3(BT), dim3(192), 0, stream,
                         hs, pairs, out);
    } else {
      const int needBlocks = (BT + 3) / 4;
      const int grid2 = (needBlocks < 2048) ? needBlocks : 2048;
      hipLaunchKernelGGL(seg_mean_generic, dim3(grid2), dim3(256), 0,
                         stream, hs, pairs, out, BT, D / 4);
    }
  } else {
    hipLaunchKernelGGL(seg_mean_search_kernel, dim3(BT), dim3(D / 4), 0, stream,
                       hs, seg, num_tokens_p, out, BS_total, D);
  }
}